// Round 13
// baseline (49.868 us; speedup 1.0000x reference)
//
#include <hip/hip_runtime.h>

#define Bb 16
#define Ll 2048
#define Ee 256
#define E4 64
#define BPB 32          // P1/k3 blocks per batch (64 rows each)
#define RPB 64
#define JT 16           // kB blocks per batch (t ep-slices)
#define FS (Ee / JT)    // 16 ep-rows per slice

// ws layout (floats). kA writes ALL P1 slots + M/bqk/kvec/beta + zeroes out.
// kB j==0 zeroes U/W and the ticket (ordered before k3 by dispatch).
#define P1_OFF 0                        // [16][32][256] row-sum partials
#define TP_OFF (P1_OFF + Bb*BPB*Ee)     // [16][16][256] t partials (ep-slices)
#define C_OFF  (TP_OFF + Bb*JT*Ee)      // [16] c
#define U_OFF  (C_OFF + Bb)             // [16][256] u accumulator
#define W_OFF  (U_OFF + Bb*Ee)          // [16] W accumulator
#define M_OFF  (W_OFF + Bb)             // [256][256] M = Wq^T Wk
#define BQK_OFF (M_OFF + Ee*Ee)         // [256] bqk = bq @ Wk
#define KV_OFF  (BQK_OFF + Ee)          // [256] kvec = Wq^T bk
#define BETA_OFF (KV_OFF + Ee)          // [1]   beta = bq.bk
#define TK_OFF  (BETA_OFF + 1)          // [16] int tickets

// kA: blocks [0,512): P1 partials (fixed-16 masked unroll; zeros if inactive);
//     i==0 zeroes out[b,:] (covers len==0 batches; tail overwrites otherwise).
//     blocks [512,768): row ep of M = Wq^T Wk; kvec[ep]; ep==0: bqk, beta.
__global__ void __launch_bounds__(256) kA(const float* __restrict__ x,
                                          const int* __restrict__ lengths,
                                          const float* __restrict__ Wq,
                                          const float* __restrict__ bq,
                                          const float* __restrict__ Wk,
                                          const float* __restrict__ bk,
                                          float* __restrict__ ws,
                                          float* __restrict__ out) {
    const int blk = blockIdx.x;
    const int tid = threadIdx.x, lane = tid & 63, wid = tid >> 6;

    if (blk < Bb * BPB) {
        const int b = blk >> 5, i = blk & 31;
        if (i == 0) out[b * Ee + tid] = 0.f;
        const int len = lengths[b];
        const int r0 = i * RPB;
        float4* slot = (float4*)(ws + P1_OFF + ((size_t)(b * BPB + i)) * Ee);
        if (r0 >= len) {
            if (tid < 64) slot[tid] = make_float4(0.f, 0.f, 0.f, 0.f);
            return;
        }
        const float4* xb = (const float4*)(x + (size_t)b * Ll * Ee);
        float4 acc = {0.f, 0.f, 0.f, 0.f};
#pragma unroll
        for (int rr = 0; rr < 16; ++rr) {
            const int r = r0 + wid + rr * 4;
            float4 v = xb[(size_t)r * E4 + lane];      // padded rows valid memory
            const bool ok = (r < len);
            acc.x += ok ? v.x : 0.f; acc.y += ok ? v.y : 0.f;
            acc.z += ok ? v.z : 0.f; acc.w += ok ? v.w : 0.f;
        }
        __shared__ float4 part[256];
        part[tid] = acc;
        __syncthreads();
        if (tid < 64) {
            float4 a = part[tid], b1 = part[64+tid], c1 = part[128+tid], d1 = part[192+tid];
            slot[tid] = make_float4(a.x+b1.x+c1.x+d1.x, a.y+b1.y+c1.y+d1.y,
                                    a.z+b1.z+c1.z+d1.z, a.w+b1.w+c1.w+d1.w);
        }
        return;
    }

    // ---- M role: row ep ----
    const int ep = blk - Bb * BPB;
    const float4* wk4 = (const float4*)Wk;
    float4 macc = {0.f, 0.f, 0.f, 0.f};
    float4 qacc = {0.f, 0.f, 0.f, 0.f};
    const bool doBqk = (ep == 0);
#pragma unroll 16
    for (int q = 0; q < 64; ++q) {
        const int f = wid * 64 + q;
        const float wq = Wq[(size_t)f * Ee + ep];      // wave-uniform broadcast
        const float4 w4 = wk4[(size_t)f * E4 + lane];
        macc.x += wq * w4.x; macc.y += wq * w4.y;
        macc.z += wq * w4.z; macc.w += wq * w4.w;
        if (doBqk) {
            const float bqf = bq[f];
            qacc.x += bqf * w4.x; qacc.y += bqf * w4.y;
            qacc.z += bqf * w4.z; qacc.w += bqf * w4.w;
        }
    }
    float kv = Wq[(size_t)(wid * 64 + lane) * Ee + ep] * bk[wid * 64 + lane];
#pragma unroll
    for (int m = 32; m; m >>= 1) kv += __shfl_xor(kv, m, 64);

    __shared__ float4 mred[4][64];
    __shared__ float4 qred[4][64];
    __shared__ float kred[4];
    mred[wid][lane] = macc;
    if (doBqk) qred[wid][lane] = qacc;
    if (lane == 0) kred[wid] = kv;
    __syncthreads();
    if (wid == 0) {
        float4 a = mred[0][lane], b1 = mred[1][lane], c1 = mred[2][lane], d1 = mred[3][lane];
        ((float4*)(ws + M_OFF + (size_t)ep * Ee))[lane] =
            make_float4(a.x+b1.x+c1.x+d1.x, a.y+b1.y+c1.y+d1.y,
                        a.z+b1.z+c1.z+d1.z, a.w+b1.w+c1.w+d1.w);
        if (lane == 0) ws[KV_OFF + ep] = kred[0] + kred[1] + kred[2] + kred[3];
    }
    if (doBqk) {
        if (wid == 1) {
            float4 a = qred[0][lane], b1 = qred[1][lane], c1 = qred[2][lane], d1 = qred[3][lane];
            ((float4*)(ws + BQK_OFF))[lane] =
                make_float4(a.x+b1.x+c1.x+d1.x, a.y+b1.y+c1.y+d1.y,
                            a.z+b1.z+c1.z+d1.z, a.w+b1.w+c1.w+d1.w);
        }
        float p = bq[tid] * bk[tid];
#pragma unroll
        for (int m = 32; m; m >>= 1) p += __shfl_xor(p, m, 64);
        __shared__ float bred[4];
        if (lane == 0) bred[wid] = p;
        __syncthreads();
        if (tid == 0) ws[BETA_OFF] = bred[0] + bred[1] + bred[2] + bred[3];
    }
}

// kB: block (b,j): Xsum via fixed-32 reduce; t-partial over ep-slice j via M;
// j==0 adds len*bqk, emits C, zeroes U/W and ticket.
__global__ void __launch_bounds__(256) kB(const int* __restrict__ lengths,
                                          float* __restrict__ ws) {
    const int b = blockIdx.y, j = blockIdx.x;
    const int tid = threadIdx.x;
    const int len = lengths[b];
    __shared__ alignas(16) float xs[Ee];
    {
        const float* P = ws + P1_OFF + (size_t)b * BPB * Ee + tid;
        float a0 = 0.f, a1 = 0.f, a2 = 0.f, a3 = 0.f;
#pragma unroll
        for (int q = 0; q < BPB; q += 4) {
            a0 += P[(size_t)(q+0) * Ee];
            a1 += P[(size_t)(q+1) * Ee];
            a2 += P[(size_t)(q+2) * Ee];
            a3 += P[(size_t)(q+3) * Ee];
        }
        xs[tid] = (a0 + a1) + (a2 + a3);
    }
    __syncthreads();
    const float* M = ws + M_OFF;
    float tp = 0.f;
#pragma unroll
    for (int q = 0; q < FS; ++q) {
        const int ep = j * FS + q;
        tp += xs[ep] * M[(size_t)ep * Ee + tid];
    }
    if (j == 0) tp += (float)len * ws[BQK_OFF + tid];
    ws[TP_OFF + ((size_t)(b * JT + j)) * Ee + tid] = tp;

    if (j == 0) {
        ws[U_OFF + b * Ee + tid] = 0.f;
        float p = xs[tid] * ws[KV_OFF + tid];
#pragma unroll
        for (int m = 32; m; m >>= 1) p += __shfl_xor(p, m, 64);
        __shared__ float cred[4];
        if ((tid & 63) == 0) cred[tid >> 6] = p;
        __syncthreads();
        if (tid == 0) {
            ws[C_OFF + b] = cred[0] + cred[1] + cred[2] + cred[3]
                          + (float)len * ws[BETA_OFF];
            ws[W_OFF + b] = 0.f;
            ((int*)ws)[TK_OFF + b] = 0;
        }
    }
}

// k3: champion stream + U/W accumulation; last active block per batch
// (ticket rendezvous in ws) stages u in LDS, projects through Wv, stores out.
__global__ void __launch_bounds__(256) k3(const float* __restrict__ x,
                                          const int* __restrict__ lengths,
                                          float* __restrict__ ws,
                                          const float* __restrict__ Wv,
                                          const float* __restrict__ bv,
                                          float* __restrict__ out) {
    const int b = blockIdx.y, i = blockIdx.x;
    const int len = lengths[b];
    const int r0 = i * RPB;
    if (r0 >= len) return;
    const int tid = threadIdx.x, lane = tid & 63, wid = tid >> 6;
    const float* TP = ws + TP_OFF;
    float* U = ws + U_OFF;
    float* W = ws + W_OFF;

    const float4* tp4 = (const float4*)(TP + (size_t)b * JT * Ee);
    float4 tv = {0.f, 0.f, 0.f, 0.f};
#pragma unroll
    for (int jj = 0; jj < JT; ++jj) {
        float4 t = tp4[(size_t)jj * E4 + lane];
        tv.x += t.x; tv.y += t.y; tv.z += t.z; tv.w += t.w;
    }
    const float cb = ws[C_OFF + b];
    const float4* xb = (const float4*)(x + (size_t)b * Ll * Ee);
    float4 uacc = {0.f, 0.f, 0.f, 0.f};
    float wacc = 0.f;
#pragma unroll
    for (int rr = 0; rr < 16; ++rr) {
        const int r = r0 + wid + rr * 4;
        float4 xv = xb[(size_t)r * E4 + lane];
        float d = xv.x*tv.x + xv.y*tv.y + xv.z*tv.z + xv.w*tv.w;
#pragma unroll
        for (int m = 32; m; m >>= 1) d += __shfl_xor(d, m, 64);
        float w = (r < len) ? (d + cb) : 0.f;
        uacc.x += w*xv.x; uacc.y += w*xv.y; uacc.z += w*xv.z; uacc.w += w*xv.w;
        wacc += w;
    }
    __shared__ float4 part[256];
    __shared__ float cw[4];
    part[tid] = uacc;
    if (lane == 0) cw[wid] = wacc;
    __syncthreads();
    if (tid < 64) {
        float4 a = part[tid], b1 = part[64+tid], c1 = part[128+tid], d1 = part[192+tid];
        float* ub = U + b * Ee + tid * 4;
        atomicAdd(ub + 0, a.x + b1.x + c1.x + d1.x);
        atomicAdd(ub + 1, a.y + b1.y + c1.y + d1.y);
        atomicAdd(ub + 2, a.z + b1.z + c1.z + d1.z);
        atomicAdd(ub + 3, a.w + b1.w + c1.w + d1.w);
    }
    if (tid == 0) atomicAdd(W + b, cw[0] + cw[1] + cw[2] + cw[3]);

    // rendezvous: barrier drains the atomics (vmcnt0), then ticket.
    __shared__ int isLast;
    __syncthreads();
    if (tid == 0) {
        __threadfence();
        const int nact = (len + RPB - 1) >> 6;         // active blocks this batch
        int old = atomicAdd((int*)ws + TK_OFF + b, 1);
        isLast = (old == nact - 1);
    }
    __syncthreads();
    if (!isLast) return;
    __threadfence();

    // tail: u -> LDS; out[b,tid] = (Wv[tid,:].u + bv[tid]*W[b]) / L
    __shared__ alignas(16) float u_sh[Ee];
    u_sh[tid] = U[b * Ee + tid];
    __syncthreads();
    const float Wb = W[b];
    const float4* wrow = (const float4*)(Wv + (size_t)tid * Ee);
    const float4* u4   = (const float4*)u_sh;
    float a0 = 0.f, a1 = 0.f, a2 = 0.f, a3 = 0.f;
#pragma unroll 8
    for (int q = 0; q < E4; q += 4) {
        float4 w0 = wrow[q+0], w1 = wrow[q+1], w2 = wrow[q+2], w3 = wrow[q+3];
        float4 v0 = u4[q+0],  v1 = u4[q+1],  v2 = u4[q+2],  v3 = u4[q+3];
        a0 += w0.x*v0.x + w0.y*v0.y + w0.z*v0.z + w0.w*v0.w;
        a1 += w1.x*v1.x + w1.y*v1.y + w1.z*v1.z + w1.w*v1.w;
        a2 += w2.x*v2.x + w2.y*v2.y + w2.z*v2.z + w2.w*v2.w;
        a3 += w3.x*v3.x + w3.y*v3.y + w3.z*v3.z + w3.w*v3.w;
    }
    out[b * Ee + tid] = ((a0 + a1) + (a2 + a3) + bv[tid] * Wb) * (1.0f / (float)Ll);
}

extern "C" void kernel_launch(void* const* d_in, const int* in_sizes, int n_in,
                              void* d_out, int out_size, void* d_ws, size_t ws_size,
                              hipStream_t stream) {
    const float* x       = (const float*)d_in[0];
    const int*   lengths = (const int*)d_in[1];
    const float* Wq      = (const float*)d_in[2];
    const float* bq      = (const float*)d_in[3];
    const float* Wk      = (const float*)d_in[4];
    const float* bk      = (const float*)d_in[5];
    const float* Wv      = (const float*)d_in[6];
    const float* bv      = (const float*)d_in[7];
    float* out = (float*)d_out;
    float* ws  = (float*)d_ws;

    kA<<<Bb * BPB + Ee, 256, 0, stream>>>(x, lengths, Wq, bq, Wk, bk, ws, out);
    kB<<<dim3(JT, Bb), 256, 0, stream>>>(lengths, ws);
    k3<<<dim3(BPB, Bb), 256, 0, stream>>>(x, lengths, ws, Wv, bv, out);
}

// Round 14
// 31.897 us; speedup vs baseline: 1.5634x; 1.5634x over previous
//
#include <hip/hip_runtime.h>

#define Bb 16
#define Ll 2048
#define Ee 256
#define E4 64
#define BPB 32          // k1/k3 blocks per batch (64 rows each)
#define RPB 64
#define JT 16           // kB blocks per batch (t f-slices)
#define FS (Ee / JT)    // 16 f-rows per slice

// ws layout (floats). All slots (P1/TP/UP/WP) are ALWAYS fully written by
// their producer (zeros when inactive) -> no zero-init, no atomics anywhere.
#define P1_OFF 0                        // [16][32][256] row-sum partials
#define TP_OFF (P1_OFF + Bb*BPB*Ee)     // [16][16][256] t partials
#define C_OFF  (TP_OFF + Bb*JT*Ee)      // [16] c
#define UP_OFF (C_OFF + Bb)             // [16][32][256] u partials
#define WP_OFF (UP_OFF + Bb*BPB*Ee)     // [16][32] w partials

// k1: partial sums of rows [i*64, i*64+64) masked -> P1[b][i][:] (zeros if inactive).
__global__ void __launch_bounds__(256) k1(const float* __restrict__ x,
                                          const int* __restrict__ lengths,
                                          float* __restrict__ P1) {
    const int b = blockIdx.y, i = blockIdx.x;
    const int tid = threadIdx.x, lane = tid & 63, wid = tid >> 6;
    const int len = lengths[b];
    const int r0 = i * RPB;
    float4* slot = (float4*)(P1 + ((size_t)(b * BPB + i)) * Ee);
    if (r0 >= len) {                          // inactive: publish zeros
        if (tid < 64) slot[tid] = make_float4(0.f, 0.f, 0.f, 0.f);
        return;
    }
    const float4* xb = (const float4*)(x + (size_t)b * Ll * Ee);
    float4 acc = {0.f, 0.f, 0.f, 0.f};
#pragma unroll
    for (int rr = 0; rr < 16; ++rr) {
        const int r = r0 + wid + rr * 4;
        float4 v = xb[(size_t)r * E4 + lane];          // padded rows valid memory
        const bool ok = (r < len);
        acc.x += ok ? v.x : 0.f; acc.y += ok ? v.y : 0.f;
        acc.z += ok ? v.z : 0.f; acc.w += ok ? v.w : 0.f;
    }
    __shared__ float4 part[256];
    part[tid] = acc;
    __syncthreads();
    if (tid < 64) {
        float4 a = part[tid], b1 = part[64+tid], c1 = part[128+tid], d1 = part[192+tid];
        slot[tid] = make_float4(a.x+b1.x+c1.x+d1.x, a.y+b1.y+c1.y+d1.y,
                                a.z+b1.z+c1.z+d1.z, a.w+b1.w+c1.w+d1.w);
    }
}

// kB: block (b,j): Xsum via fixed-32 unrolled reduce; full s; t-slice j.
// j==0 also emits C. (No zero-init duties.)
__global__ void __launch_bounds__(256) kB(const float* __restrict__ P1,
                                          const int* __restrict__ lengths,
                                          const float* __restrict__ Wq,
                                          const float* __restrict__ bq,
                                          const float* __restrict__ Wk,
                                          const float* __restrict__ bk,
                                          float* __restrict__ TP, float* __restrict__ C) {
    const int b = blockIdx.y, j = blockIdx.x;
    const int tid = threadIdx.x;
    const int len = lengths[b];
    __shared__ alignas(16) float xs[Ee];
    __shared__ alignas(16) float s_sh[Ee];
    {
        const float* P = P1 + (size_t)b * BPB * Ee + tid;
        float a0 = 0.f, a1 = 0.f, a2 = 0.f, a3 = 0.f;
#pragma unroll
        for (int q = 0; q < BPB; q += 4) {             // 32 independent loads
            a0 += P[(size_t)(q+0) * Ee];
            a1 += P[(size_t)(q+1) * Ee];
            a2 += P[(size_t)(q+2) * Ee];
            a3 += P[(size_t)(q+3) * Ee];
        }
        xs[tid] = (a0 + a1) + (a2 + a3);
    }
    __syncthreads();
    {
        const float4* wrow = (const float4*)(Wq + (size_t)tid * Ee);
        const float4* x4   = (const float4*)xs;
        float acc = 0.f;
#pragma unroll 16
        for (int q = 0; q < E4; ++q) {
            float4 w = wrow[q]; float4 v = x4[q];
            acc += w.x*v.x + w.y*v.y + w.z*v.z + w.w*v.w;
        }
        s_sh[tid] = acc + (float)len * bq[tid];
    }
    __syncthreads();
    float tp = 0.f;
#pragma unroll
    for (int f0 = 0; f0 < FS; ++f0) {                  // 16 independent Wk rows
        const int f = j * FS + f0;
        tp += s_sh[f] * Wk[(size_t)f * Ee + tid];
    }
    TP[((size_t)(b * JT + j)) * Ee + tid] = tp;
    if (j == 0) {
        float p = s_sh[tid] * bk[tid];
#pragma unroll
        for (int m = 32; m; m >>= 1) p += __shfl_xor(p, m, 64);
        __shared__ float cred[4];
        if ((tid & 63) == 0) cred[tid >> 6] = p;
        __syncthreads();
        if (tid == 0) C[b] = cred[0] + cred[1] + cred[2] + cred[3];
    }
}

// k3: tv from fixed-16 TP reduce; fixed-16 masked stream over 64 rows;
// block-reduce u,w; PLAIN slot stores (no atomics). Zeros if inactive.
__global__ void __launch_bounds__(256) k3(const float* __restrict__ x,
                                          const int* __restrict__ lengths,
                                          const float* __restrict__ TP,
                                          const float* __restrict__ C,
                                          float* __restrict__ UP,
                                          float* __restrict__ WP) {
    const int b = blockIdx.y, i = blockIdx.x;
    const int len = lengths[b];
    const int r0 = i * RPB;
    const int tid = threadIdx.x, lane = tid & 63, wid = tid >> 6;
    float4* uslot = (float4*)(UP + ((size_t)(b * BPB + i)) * Ee);
    if (r0 >= len) {                       // inactive: publish zeros
        if (tid < 64) uslot[tid] = make_float4(0.f, 0.f, 0.f, 0.f);
        if (tid == 0) WP[b * BPB + i] = 0.f;
        return;
    }
    const float4* tp4 = (const float4*)(TP + (size_t)b * JT * Ee);
    float4 tv = {0.f, 0.f, 0.f, 0.f};
#pragma unroll
    for (int jj = 0; jj < JT; ++jj) {      // 16 independent loads
        float4 t = tp4[(size_t)jj * E4 + lane];
        tv.x += t.x; tv.y += t.y; tv.z += t.z; tv.w += t.w;
    }
    const float cb = C[b];
    const float4* xb = (const float4*)(x + (size_t)b * Ll * Ee);
    float4 uacc = {0.f, 0.f, 0.f, 0.f};
    float wacc = 0.f;
#pragma unroll
    for (int rr = 0; rr < 16; ++rr) {
        const int r = r0 + wid + rr * 4;
        float4 xv = xb[(size_t)r * E4 + lane];         // padded rows valid memory
        float d = xv.x*tv.x + xv.y*tv.y + xv.z*tv.z + xv.w*tv.w;
#pragma unroll
        for (int m = 32; m; m >>= 1) d += __shfl_xor(d, m, 64);
        float w = (r < len) ? (d + cb) : 0.f;          // mask after reduce
        uacc.x += w*xv.x; uacc.y += w*xv.y; uacc.z += w*xv.z; uacc.w += w*xv.w;
        wacc += w;                                     // wave-uniform
    }
    __shared__ float4 part[256];
    __shared__ float cw[4];
    part[tid] = uacc;
    if (lane == 0) cw[wid] = wacc;
    __syncthreads();
    if (tid < 64) {
        float4 a = part[tid], b1 = part[64+tid], c1 = part[128+tid], d1 = part[192+tid];
        uslot[tid] = make_float4(a.x+b1.x+c1.x+d1.x, a.y+b1.y+c1.y+d1.y,
                                 a.z+b1.z+c1.z+d1.z, a.w+b1.w+c1.w+d1.w);
    }
    if (tid == 0) WP[b * BPB + i] = cw[0] + cw[1] + cw[2] + cw[3];
}

// k4: block (b,j): reduce 32 u-slots (fixed loads) -> u_sh; reduce 32 w-slots;
// out[b, j*64 + lane] via 4-wave f-split Wv dot; single plain store.
__global__ void __launch_bounds__(256) k4(const float* __restrict__ UP,
                                          const float* __restrict__ WP,
                                          const float* __restrict__ Wv,
                                          const float* __restrict__ bv,
                                          float* __restrict__ out) {
    const int b = blockIdx.y, j = blockIdx.x;   // j in 0..3
    const int tid = threadIdx.x, lane = tid & 63, wid = tid >> 6;
    __shared__ alignas(16) float u_sh[Ee];
    __shared__ float red[4][64];
    __shared__ float w_sh;
    {
        const float* P = UP + (size_t)b * BPB * Ee + tid;
        float a0 = 0.f, a1 = 0.f, a2 = 0.f, a3 = 0.f;
#pragma unroll
        for (int q = 0; q < BPB; q += 4) {             // 32 independent loads
            a0 += P[(size_t)(q+0) * Ee];
            a1 += P[(size_t)(q+1) * Ee];
            a2 += P[(size_t)(q+2) * Ee];
            a3 += P[(size_t)(q+3) * Ee];
        }
        u_sh[tid] = (a0 + a1) + (a2 + a3);
    }
    if (wid == 0) {                                    // 32 w-partials, wave 0
        float p = (lane < BPB) ? WP[b * BPB + lane] : 0.f;
#pragma unroll
        for (int m = 32; m; m >>= 1) p += __shfl_xor(p, m, 64);
        if (lane == 0) w_sh = p;
    }
    __syncthreads();
    const int e = j * 64 + lane;
    const float4* wv = (const float4*)(Wv + (size_t)e * Ee);
    const float4* u4 = (const float4*)u_sh;
    float acc = 0.f;
#pragma unroll
    for (int q = 0; q < 16; ++q) {
        float4 w = wv[wid * 16 + q]; float4 v = u4[wid * 16 + q];
        acc += w.x*v.x + w.y*v.y + w.z*v.z + w.w*v.w;
    }
    red[wid][lane] = acc;
    __syncthreads();
    if (wid == 0) {
        float r = red[0][lane] + red[1][lane] + red[2][lane] + red[3][lane];
        out[b * Ee + e] = (r + bv[e] * w_sh) * (1.0f / (float)Ll);
    }
}

extern "C" void kernel_launch(void* const* d_in, const int* in_sizes, int n_in,
                              void* d_out, int out_size, void* d_ws, size_t ws_size,
                              hipStream_t stream) {
    const float* x       = (const float*)d_in[0];
    const int*   lengths = (const int*)d_in[1];
    const float* Wq      = (const float*)d_in[2];
    const float* bq      = (const float*)d_in[3];
    const float* Wk      = (const float*)d_in[4];
    const float* bk      = (const float*)d_in[5];
    const float* Wv      = (const float*)d_in[6];
    const float* bv      = (const float*)d_in[7];
    float* out = (float*)d_out;
    float* ws  = (float*)d_ws;

    k1<<<dim3(BPB, Bb), 256, 0, stream>>>(x, lengths, ws + P1_OFF);
    kB<<<dim3(JT, Bb), 256, 0, stream>>>(ws + P1_OFF, lengths, Wq, bq, Wk, bk,
                                         ws + TP_OFF, ws + C_OFF);
    k3<<<dim3(BPB, Bb), 256, 0, stream>>>(x, lengths, ws + TP_OFF, ws + C_OFF,
                                          ws + UP_OFF, ws + WP_OFF);
    k4<<<dim3(4, Bb), 256, 0, stream>>>(ws + UP_OFF, ws + WP_OFF, Wv, bv, out);
}